// Round 10
// baseline (178.097 us; speedup 1.0000x reference)
//
#include <hip/hip_runtime.h>
#include <hip/hip_bf16.h>
#include <math.h>

#define N 512
#define D 256
#define NH 8
#define HD 32
#define NN (N * N)

typedef _Float16 h2 __attribute__((ext_vector_type(2)));      // arithmetic type
typedef __fp16 h2raw __attribute__((ext_vector_type(2)));     // builtin i/o type
union H2U { h2 h; h2raw r; float f; };

__device__ __forceinline__ h2 cvtpk(float a, float b) {
    H2U u; u.r = __builtin_amdgcn_cvt_pkrtz(a, b); return u.h;
}
// v_dot2_f32_f16: c += a.x*b.x + a.y*b.y (f32 accum); b given as float bits
__device__ __forceinline__ float fdot2w(h2 a, float wbits, float c) {
    H2U ua, uw; ua.h = a; uw.f = wbits;
    return __builtin_amdgcn_fdot2(ua.r, uw.r, c, false);
}

// packed-f16 deg-4 silu; inputs |x|<=0.25, abs err ~1e-4. (validated r9)
__device__ __forceinline__ h2 silu_pk(h2 x) {
    const _Float16 kA = (_Float16)(-2.083333333e-2f);
    const _Float16 kB = (_Float16)(0.25f);
    const _Float16 kC = (_Float16)(0.5f);
    h2 vA = {kA, kA}, vB = {kB, kB}, vC = {kC, kC};
    h2 x2 = x * x;
    h2 t = x2 * vA + vB;
    return x2 * t + vC * x;
}

// ---------------------------------------------------------------------------
// K1: blocks 0..383   : qkv GEMM, 32x32 output tiles, K-chunked LDS staging
//     blocks 384..895 : coord projections (abT transposed, av row-major)
//     blocks 896..959 : Wv2T transpose (for coalesced fused-epilogue reads)
// ---------------------------------------------------------------------------
__global__ __launch_bounds__(256) void prep_kernel(
    const float* __restrict__ x, const float* __restrict__ W,
    const float* __restrict__ bias, const float* __restrict__ coords,
    const float* __restrict__ Wb1, const float* __restrict__ Wv1,
    const float* __restrict__ Wv2,
    float* __restrict__ q, float* __restrict__ k, float* __restrict__ v,
    float* __restrict__ abT, float* __restrict__ av,
    float* __restrict__ Wv2T) {
    int bid = blockIdx.x, tid = threadIdx.x;
    if (bid < 384) {
        int tt = bid & 15, ot = bid >> 4;
        __shared__ float xs[32][68];
        __shared__ float wsl[32][68];
        int ty = tid >> 4, tx = tid & 15;
        float acc00 = 0.f, acc01 = 0.f, acc10 = 0.f, acc11 = 0.f;
        for (int k0 = 0; k0 < 256; k0 += 64) {
            __syncthreads();
#pragma unroll
            for (int it = 0; it < 2; ++it) {
                int f4i = it * 256 + tid;
                int r = f4i >> 4, kkf = (f4i & 15) * 4;
                *(float4*)&xs[r][kkf] =
                    *(const float4*)&x[(tt * 32 + r) * 256 + k0 + kkf];
                *(float4*)&wsl[r][kkf] =
                    *(const float4*)&W[(ot * 32 + r) * 256 + k0 + kkf];
            }
            __syncthreads();
#pragma unroll 8
            for (int kk = 0; kk < 64; ++kk) {
                float x0 = xs[ty * 2][kk], x1 = xs[ty * 2 + 1][kk];
                float w0 = wsl[tx * 2][kk], w1 = wsl[tx * 2 + 1][kk];
                acc00 += x0 * w0; acc01 += x0 * w1;
                acc10 += x1 * w0; acc11 += x1 * w1;
            }
        }
        int tokb = tt * 32 + ty * 2, ob = ot * 32 + tx * 2;
        float accs[2][2] = {{acc00, acc01}, {acc10, acc11}};
#pragma unroll
        for (int a = 0; a < 2; ++a)
#pragma unroll
            for (int b = 0; b < 2; ++b) {
                int o = ob + b, tok = tokb + a;
                float r = accs[a][b] + bias[o];
                int oc = o >> 8, col = o & 255;
                float* outp = (oc == 0) ? q : (oc == 1) ? k : v;
                outp[tok * 256 + col] = r;
            }
    } else if (bid < 896) {
        int j = bid - 384;
        float cx = coords[j * 3 + 0], cy = coords[j * 3 + 1], cz = coords[j * 3 + 2];
        abT[tid * N + j] = Wb1[tid * 3 + 0] * cx + Wb1[tid * 3 + 1] * cy + Wb1[tid * 3 + 2] * cz;
        av[j * D + tid]  = Wv1[tid * 3 + 0] * cx + Wv1[tid * 3 + 1] * cy + Wv1[tid * 3 + 2] * cz;
    } else {
        int r0 = (bid - 896) * 4;
#pragma unroll
        for (int rr = 0; rr < 4; ++rr) {
            int row = r0 + rr;
            Wv2T[tid * 256 + row] = Wv2[row * 256 + tid];
        }
    }
}

// ---------------------------------------------------------------------------
// K2: sc[h][i][j] = (q_h[i]·k_h[j]) / sqrt(32)   (unchanged; sc is now
// read-only downstream — weights never round-trip to global)
// ---------------------------------------------------------------------------
__global__ __launch_bounds__(256) void qk_kernel(
    const float* __restrict__ q, const float* __restrict__ k,
    float* __restrict__ sc) {
    int bid = blockIdx.x;
    int h = bid >> 6, rem = bid & 63, it = rem >> 3, jt = rem & 7;
    int i0 = it * 64, j0 = jt * 64;
    int tid = threadIdx.x;
    __shared__ float qsT[32][65];
    __shared__ float ksT[32][65];
    for (int idx = tid; idx < 64 * 32; idx += 256) {
        int r = idx >> 5, d = idx & 31;
        qsT[d][r] = q[(i0 + r) * D + h * HD + d];
        ksT[d][r] = k[(j0 + r) * D + h * HD + d];
    }
    __syncthreads();
    int ti = tid >> 4, tj = tid & 15;
    float acc[4][4] = {{0.f}};
#pragma unroll 4
    for (int d = 0; d < 32; ++d) {
        float qa[4], kb[4];
#pragma unroll
        for (int a = 0; a < 4; ++a) qa[a] = qsT[d][ti * 4 + a];
#pragma unroll
        for (int b = 0; b < 4; ++b) kb[b] = ksT[d][tj * 4 + b];
#pragma unroll
        for (int a = 0; a < 4; ++a)
#pragma unroll
            for (int b = 0; b < 4; ++b) acc[a][b] += qa[a] * kb[b];
    }
    const float scale = 0.17677669529663687f;
#pragma unroll
    for (int a = 0; a < 4; ++a) {
        float4 o = make_float4(acc[a][0] * scale, acc[a][1] * scale,
                               acc[a][2] * scale, acc[a][3] * scale);
        *(float4*)&sc[h * NN + (i0 + ti * 4 + a) * N + j0 + tj * 4] = o;
    }
}

// ---------------------------------------------------------------------------
// K3 (fused): bias + softmax + value + epilogue, one block per query.
// 1024 threads, grid N, ~58 KB LDS -> 2 blocks/CU = 8 waves/SIMD.
//
// Phase A (threads = (cg, j)): bias via fdot2 c-pair loop (K3 r9 logic),
//   bpart LDS reduce, softmax; weights packed f16 pairs -> wpk LDS (no
//   global round-trip).
// Phase B (threads = (jg, c)): value j-pair loop via fdot2 reading wpk;
//   partials -> spart (unioned over phase-A scratch) -> stot.
// Phase C: Wv2 epilogue from stot (Wv2T coalesced) + base + biases -> out.
// ---------------------------------------------------------------------------
__global__ __launch_bounds__(1024, 8) void fused_bsv_kernel(
    const float* __restrict__ abT, const float* __restrict__ bb1,
    const float* __restrict__ Wb2, const float* __restrict__ bb2,
    const float* __restrict__ sc,
    const float* __restrict__ av, const float* __restrict__ bv1,
    const float* __restrict__ vbuf,
    const float* __restrict__ Wv2T, const float* __restrict__ bv2,
    float* __restrict__ out) {
    // LDS layout (floats), 14720 total = 58880 B:
    //  wpk   [0,2048)      : [jp=256][h=8] packed f16 pair bits  (A->B)
    //  R     [2048,11648)  : A: wb2p 1024 | abip 128 | redm 128 | reds 128 | bpart 8192
    //                        B: spart [jg=4][h=8][c=256]=8192 | bbuf [4][256]=1024
    //  stot  [11648,13696) : [h=8][c=256]                       (B->C)
    //  rpart [13696,14720) : [sg=4][c=256]
    __shared__ float smem[14720];
    float* wpk  = smem;
    float* R    = smem + 2048;
    float* wb2p = R;                   // [cp=128][h=8]
    h2*    abip = (h2*)(R + 1024);     // [128]
    float* redm = R + 1152;            // [h][16]
    float* reds = R + 1280;            // [h][16]
    float* bpart = R + 1408;           // [h][cg=2][j=512]
    float* spart = R;                  // phase B (overwrites A scratch)
    float* bbuf  = R + 8192;
    float* stot  = smem + 11648;
    float* rpart = smem + 13696;

    int i = blockIdx.x;
    int tid = threadIdx.x;

    // ---- Phase A: bias + softmax --------------------------------------
    int cg = tid >> 9, j = tid & (N - 1);
    if (tid < 128) {
#pragma unroll
        for (int h = 0; h < 8; ++h) {
            H2U u;
            u.h = cvtpk(Wb2[h * D + 2 * tid], Wb2[h * D + 2 * tid + 1]);
            wb2p[tid * 8 + h] = u.f;
        }
        float a0 = abT[(2 * tid) * N + i] + bb1[2 * tid];
        float a1 = abT[(2 * tid + 1) * N + i] + bb1[2 * tid + 1];
        abip[tid] = cvtpk(a0, a1);
    }
    __syncthreads();

    float b[8] = {0.f, 0.f, 0.f, 0.f, 0.f, 0.f, 0.f, 0.f};
    const float* aj = abT + j;
    int cp0 = cg * 64;
#pragma unroll 4
    for (int cc = 0; cc < 64; ++cc) {
        int cp = cp0 + cc;
        float a0 = aj[(2 * cp) * N];       // coalesced over j
        float a1 = aj[(2 * cp + 1) * N];
        h2 ap = cvtpk(a0, a1);
        h2 d = abip[cp] - ap;              // broadcast LDS read
        h2 hb = silu_pk(d);
        float4 wv0 = *(const float4*)&wb2p[cp * 8];      // broadcast b128
        float4 wv1 = *(const float4*)&wb2p[cp * 8 + 4];
        b[0] = fdot2w(hb, wv0.x, b[0]);
        b[1] = fdot2w(hb, wv0.y, b[1]);
        b[2] = fdot2w(hb, wv0.z, b[2]);
        b[3] = fdot2w(hb, wv0.w, b[3]);
        b[4] = fdot2w(hb, wv1.x, b[4]);
        b[5] = fdot2w(hb, wv1.y, b[5]);
        b[6] = fdot2w(hb, wv1.z, b[6]);
        b[7] = fdot2w(hb, wv1.w, b[7]);
    }
#pragma unroll
    for (int h = 0; h < 8; ++h) bpart[h * 1024 + cg * 512 + j] = b[h];
    __syncthreads();

    float s[8];
#pragma unroll
    for (int h = 0; h < 8; ++h)
        s[h] = sc[h * NN + i * N + j] + bpart[h * 1024 + j] +
               bpart[h * 1024 + 512 + j] + bb2[h];

    int wid = tid >> 6, lane = tid & 63;
#pragma unroll
    for (int h = 0; h < 8; ++h) {
        float m = s[h];
#pragma unroll
        for (int mask = 32; mask >= 1; mask >>= 1)
            m = fmaxf(m, __shfl_xor(m, mask));
        if (lane == 0) redm[h * 16 + wid] = m;
    }
    __syncthreads();
    float e[8];
#pragma unroll
    for (int h = 0; h < 8; ++h) {
        float m = redm[h * 16];
#pragma unroll
        for (int w = 1; w < 8; ++w) m = fmaxf(m, redm[h * 16 + w]);  // waves 0-7 cover all j
        e[h] = __expf(s[h] - m);
        float sum = e[h];
#pragma unroll
        for (int mask = 32; mask >= 1; mask >>= 1)
            sum += __shfl_xor(sum, mask);
        if (lane == 0) reds[h * 16 + wid] = sum;
    }
    __syncthreads();
    // weights (both halves duplicate rows -> factor 2/sum); cg0 packs pairs
    float wv[8];
#pragma unroll
    for (int h = 0; h < 8; ++h) {
        float sum = reds[h * 16];
#pragma unroll
        for (int w = 1; w < 16; ++w) sum += reds[h * 16 + w];
        wv[h] = e[h] * (2.0f * __builtin_amdgcn_rcpf(sum));
    }
    if (cg == 0) {   // waves 0-7: uniform branch, shfl is wave-local
#pragma unroll
        for (int h = 0; h < 8; ++h) {
            float hi = __shfl_down(wv[h], 1);
            if (!(j & 1)) {
                H2U u;
                u.h = cvtpk(wv[h], hi);
                wpk[(j >> 1) * 8 + h] = u.f;
            }
        }
    }
    __syncthreads();

    // ---- Phase B: value pass -----------------------------------------
    int jg = tid >> 8, c = tid & (D - 1);
    float avi = av[i * D + c] + bv1[c];
    h2 avip = cvtpk(avi, avi);
    float sv[8] = {0.f, 0.f, 0.f, 0.f, 0.f, 0.f, 0.f, 0.f};
    float bacc = 0.f;
    int ht = c >> 5;
#pragma unroll 2
    for (int jj = 0; jj < 64; ++jj) {
        int j0 = jg * 128 + 2 * jj;
        int jp = jg * 64 + jj;
        float a0 = av[j0 * D + c];          // coalesced
        float a1 = av[(j0 + 1) * D + c];
        float v0 = vbuf[j0 * D + c];
        float v1 = vbuf[(j0 + 1) * D + c];
        h2 ap = cvtpk(a0, a1);
        h2 vp = cvtpk(v0, v1);
        h2 hv = silu_pk(avip - ap);
        float4 wa = *(const float4*)&wpk[jp * 8];        // bcast b128
        float4 wb4 = *(const float4*)&wpk[jp * 8 + 4];
        sv[0] = fdot2w(hv, wa.x, sv[0]);
        sv[1] = fdot2w(hv, wa.y, sv[1]);
        sv[2] = fdot2w(hv, wa.z, sv[2]);
        sv[3] = fdot2w(hv, wa.w, sv[3]);
        sv[4] = fdot2w(hv, wb4.x, sv[4]);
        sv[5] = fdot2w(hv, wb4.y, sv[5]);
        sv[6] = fdot2w(hv, wb4.z, sv[6]);
        sv[7] = fdot2w(hv, wb4.w, sv[7]);
        bacc = fdot2w(vp, wpk[jp * 8 + ht], bacc);
    }
    // spart overwrites phase-A scratch: all reads of that region completed
    // before the packing barrier above.
#pragma unroll
    for (int h = 0; h < 8; ++h) spart[jg * 2048 + h * 256 + c] = sv[h];
    bbuf[jg * 256 + c] = bacc;
    __syncthreads();
    for (int e2 = tid; e2 < 2048; e2 += 1024)
        stot[e2] = spart[e2] + spart[2048 + e2] + spart[4096 + e2] +
                   spart[6144 + e2];
    __syncthreads();

    // ---- Phase C: Wv2 epilogue ---------------------------------------
    int sg = tid >> 8;                 // c2-quarter
    const float* srow = &stot[(c >> 5) * 256];
    float r = 0.f;
    int c20 = sg * 64;
#pragma unroll 8
    for (int c2 = 0; c2 < 64; ++c2)
        r += Wv2T[(c20 + c2) * 256 + c] * srow[c20 + c2];  // coalesced/bcast
    rpart[sg * 256 + c] = r;
    __syncthreads();
    if (sg == 0) {
        float bs = bbuf[c] + bbuf[256 + c] + bbuf[512 + c] + bbuf[768 + c];
        out[i * D + c] = bv2[c] + bs + rpart[c] + rpart[256 + c] +
                         rpart[512 + c] + rpart[768 + c];
    }
}

extern "C" void kernel_launch(void* const* d_in, const int* in_sizes, int n_in,
                              void* d_out, int out_size, void* d_ws, size_t ws_size,
                              hipStream_t stream) {
    const float* x      = (const float*)d_in[0];
    const float* coords = (const float*)d_in[1];
    const float* Wqkv   = (const float*)d_in[2];
    const float* bqkv   = (const float*)d_in[3];
    const float* Wb1    = (const float*)d_in[4];
    const float* bb1    = (const float*)d_in[5];
    const float* Wb2    = (const float*)d_in[6];
    const float* bb2    = (const float*)d_in[7];
    const float* Wv1    = (const float*)d_in[8];
    const float* bv1    = (const float*)d_in[9];
    const float* Wv2    = (const float*)d_in[10];
    const float* bv2    = (const float*)d_in[11];

    float* ws   = (float*)d_ws;
    float* q    = ws;                  // 512*256
    float* k    = q + N * D;
    float* v    = k + N * D;
    float* abT  = v + N * D;           // 256*512
    float* av   = abT + D * N;         // 512*256
    float* sc   = av + N * D;          // 8*512*512 (scores, read-only after K2)
    float* Wv2T = sc + 8 * NN;         // 256*256   (total ~9.4 MB)
    float* out  = (float*)d_out;

    prep_kernel<<<960, 256, 0, stream>>>(x, Wqkv, bqkv, coords, Wb1, Wv1, Wv2,
                                         q, k, v, abT, av, Wv2T);
    qk_kernel<<<512, 256, 0, stream>>>(q, k, sc);
    fused_bsv_kernel<<<N, 1024, 0, stream>>>(abT, bb1, Wb2, bb2, sc,
                                             av, bv1, v, Wv2T, bv2, out);
}